// Round 3
// baseline (246.287 us; speedup 1.0000x reference)
//
#include <hip/hip_runtime.h>
#include <hip/hip_bf16.h>
#include <cmath>

// Problem constants
#define S_LEN 2048
#define HIDN  1024
#define NHEAD 16
#define HDIM  64
#define NBAT  2

static constexpr long NA = (long)NBAT * S_LEN * HIDN;  // hidden elems
static constexpr long NW = (long)HIDN * HIDN;          // per weight
static constexpr long NM = (long)NBAT * S_LEN * S_LEN; // struct mask elems
static constexpr long NAM = (long)NBAT * S_LEN;        // amask elems

typedef __attribute__((ext_vector_type(8))) __bf16 bf16x8;
typedef __attribute__((ext_vector_type(4))) float f32x4;
typedef __attribute__((ext_vector_type(16))) float f32x16;
typedef __attribute__((ext_vector_type(4))) unsigned short u16x4;

#define LOG2E 1.44269504088896340736f

__device__ __forceinline__ unsigned short f2bf(float f) {
  __hip_bfloat16 h = __float2bfloat16(f);
  unsigned short u;
  __builtin_memcpy(&u, &h, 2);
  return u;
}

__device__ __forceinline__ float bfu2f(unsigned short u) {
  unsigned v = (unsigned)u << 16;
  float f;
  __builtin_memcpy(&f, &v, 4);
  return f;
}

// packed f32->bf16 RNE: low16 = bf16(a), high16 = bf16(b); 1 instr
__device__ __forceinline__ unsigned cvtpk(float a, float b) {
  unsigned r;
  asm volatile("v_cvt_pk_bf16_f32 %0, %1, %2" : "=v"(r) : "v"(a), "v"(b));
  return r;
}

__device__ __forceinline__ void gload_lds16(const void* g, void* l) {
  __builtin_amdgcn_global_load_lds(
      (const __attribute__((address_space(1))) void*)g,
      (__attribute__((address_space(3))) void*)l, 16, 0, 0);
}

// ---------------- kernel 1: fp32 -> bf16 conversions (+ amask prescale) ----------------
__global__ __launch_bounds__(256) void convert_kernel(
    const float* __restrict__ hs, const float* __restrict__ wq,
    const float* __restrict__ wk, const float* __restrict__ wv,
    const float* __restrict__ mask, const float* __restrict__ amask,
    __hip_bfloat16* __restrict__ Abf, __hip_bfloat16* __restrict__ Wcat,
    __hip_bfloat16* __restrict__ Mbf, float* __restrict__ amg) {
  const long tot4 = (NA + 3 * NW + NM + NAM) >> 2;
  for (long i4 = (long)blockIdx.x * blockDim.x + threadIdx.x; i4 < tot4;
       i4 += (long)gridDim.x * blockDim.x) {
    long i = i4 << 2;
    if (i < NA + 3 * NW + NM) {
      const float* s;
      __hip_bfloat16* dq;
      if (i < NA)               { s = hs + i;                   dq = Abf + i; }
      else if (i < NA + NW)     { s = wq + (i - NA);            dq = Wcat + (i - NA); }
      else if (i < NA + 2 * NW) { s = wk + (i - NA - NW);       dq = Wcat + (i - NA); }
      else if (i < NA + 3 * NW) { s = wv + (i - NA - 2 * NW);   dq = Wcat + (i - NA); }
      else                      { s = mask + (i - NA - 3 * NW); dq = Mbf + (i - NA - 3 * NW); }
      float4 v = *(const float4*)s;
      union { unsigned short u[4]; uint2 p; } o;
      o.u[0] = f2bf(v.x); o.u[1] = f2bf(v.y); o.u[2] = f2bf(v.z); o.u[3] = f2bf(v.w);
      *(uint2*)dq = o.p;
    } else {
      long j = i - (NA + 3 * NW + NM);
      float4 v = *(const float4*)(amask + j);
      v.x *= LOG2E; v.y *= LOG2E; v.z *= LOG2E; v.w *= LOG2E;
      *(float4*)(amg + j) = v;
    }
  }
}

// ---------------- kernel 2: QKV GEMM (m97 structure) ----------------
// q output pre-scaled by c2 = log2(e)/sqrt(HD) so attn scores are log2-domain
__global__ __launch_bounds__(256) void qkv_gemm(
    const __hip_bfloat16* __restrict__ A, const __hip_bfloat16* __restrict__ Bw,
    const float* __restrict__ bq, const float* __restrict__ bk,
    const float* __restrict__ bv, __hip_bfloat16* __restrict__ qb,
    __hip_bfloat16* __restrict__ kb, __hip_bfloat16* __restrict__ vb) {
  __shared__ __hip_bfloat16 sA[128 * 32];
  __shared__ __hip_bfloat16 sB[128 * 32];

  int bid = blockIdx.x;
  int cpx = gridDim.x >> 3;
  int wg = (bid & 7) * cpx + (bid >> 3);
  int bm = wg / 24, bn = wg % 24;
  int tid = threadIdx.x, lane = tid & 63, wid = tid >> 6;
  int wr = wid >> 1, wc = wid & 1;
  int lr = lane & 15, hi = lane >> 4;
  int srow = lane >> 2, scol = (lane & 3) * 8;

  f32x4 acc[4][4] = {};

  for (int kt = 0; kt < 32; ++kt) {
    int k0 = kt * 32;
#pragma unroll
    for (int cc = 0; cc < 2; ++cc) {
      int c = wid * 2 + cc;
      const __hip_bfloat16* ga =
          A + ((size_t)(bm * 128 + c * 16 + srow) * 1024 + k0 + scol);
      gload_lds16(ga, (char*)sA + c * 1024);
      const __hip_bfloat16* gb =
          Bw + ((size_t)(bn * 128 + c * 16 + srow) * 1024 + k0 + scol);
      gload_lds16(gb, (char*)sB + c * 1024);
    }
    __syncthreads();
    bf16x8 af[4], bf[4];
#pragma unroll
    for (int mt = 0; mt < 4; ++mt)
      af[mt] = *(const bf16x8*)((const char*)sA +
                                ((wr * 64 + mt * 16 + lr) * 32 + hi * 8) * 2);
#pragma unroll
    for (int nt = 0; nt < 4; ++nt)
      bf[nt] = *(const bf16x8*)((const char*)sB +
                                ((wc * 64 + nt * 16 + lr) * 32 + hi * 8) * 2);
#pragma unroll
    for (int mt = 0; mt < 4; ++mt)
#pragma unroll
      for (int nt = 0; nt < 4; ++nt)
        acc[mt][nt] =
            __builtin_amdgcn_mfma_f32_16x16x32_bf16(af[mt], bf[nt], acc[mt][nt], 0, 0, 0);
    __syncthreads();
  }

  const float c2 = LOG2E / 8.0f;
#pragma unroll
  for (int nt = 0; nt < 4; ++nt) {
    int nb = bn * 128 + wc * 64 + nt * 16;
    int t = nb >> 10;
    int rem = nb & 1023;
    const float* bp = (t == 0) ? bq : (t == 1) ? bk : bv;
    __hip_bfloat16* ob = (t == 0) ? qb : (t == 1) ? kb : vb;
    float scl = (t == 0) ? c2 : 1.0f;
    int h = rem >> 6, d0 = rem & 63;
    float bias = bp[rem + lr];
    int d = d0 + lr;
#pragma unroll
    for (int mt = 0; mt < 4; ++mt) {
#pragma unroll
      for (int r = 0; r < 4; ++r) {
        int m = bm * 128 + wr * 64 + mt * 16 + hi * 4 + r;
        int b = m >> 11, s = m & 2047;
        size_t off = (((size_t)(b * NHEAD + h)) * S_LEN + s) * HDIM + d;
        ob[off] = __float2bfloat16((acc[mt][nt][r] + bias) * scl);
      }
    }
  }
}

// ---------------- kernel 3: V -> V^T  ([bh][s][d] -> [bh][d][s]) ----------------
__global__ __launch_bounds__(256) void vtrans_kernel(
    const __hip_bfloat16* __restrict__ vb, __hip_bfloat16* __restrict__ vt) {
  __shared__ __hip_bfloat16 tile[64][72];
  int bh = blockIdx.x >> 5;
  int st = blockIdx.x & 31;
  int t = threadIdx.x;
  int r8 = t >> 3, c8 = (t & 7) * 8;
#pragma unroll
  for (int p = 0; p < 2; ++p) {
    int row = p * 32 + r8;
    bf16x8 v = *(const bf16x8*)(vb + ((size_t)bh * S_LEN + st * 64 + row) * HDIM + c8);
    *(bf16x8*)&tile[row][c8] = v;
  }
  __syncthreads();
#pragma unroll
  for (int p = 0; p < 2; ++p) {
    int d = p * 32 + r8;
    union { unsigned short u[8]; bf16x8 v; } o;
#pragma unroll
    for (int j = 0; j < 8; ++j) {
      __hip_bfloat16 e = tile[c8 + j][d];
      __builtin_memcpy(&o.u[j], &e, 2);
    }
    *(bf16x8*)(vt + ((size_t)bh * HDIM + d) * S_LEN + st * 64 + c8) = o.v;
  }
}

// ---------------- kernel 4: barrier-free flash attention, swapped-QK^T ----------------
// 4 independent waves per block, each owns 32 q-rows; KV-step = 128 (4 sub-tiles)
// K, V^T, masks read directly from global (L1/L2-resident) -- no LDS, no syncthreads
__global__ __launch_bounds__(256, 2) void attn_kernel(
    const __hip_bfloat16* __restrict__ qb, const __hip_bfloat16* __restrict__ kbuf,
    const __hip_bfloat16* __restrict__ vt, const __hip_bfloat16* __restrict__ Mbf,
    const float* __restrict__ amg, const float* __restrict__ gate,
    float* __restrict__ out) {
  int bi = blockIdx.x >> 8;
  int qt = (blockIdx.x >> 4) & 15;
  int h = blockIdx.x & 15;
  int bh = bi * NHEAD + h;
  int lane = threadIdx.x & 63, wid = threadIdx.x >> 6;
  int l31 = lane & 31, hi2 = lane >> 5;
  int qrow = qt * 128 + wid * 32 + l31;
  float g2 = gate[h] * LOG2E;

  const __hip_bfloat16* Kb = kbuf + (size_t)bh * S_LEN * HDIM;
  const __hip_bfloat16* Vb = vt + (size_t)bh * HDIM * S_LEN;
  const unsigned short* mbase =
      (const unsigned short*)Mbf + ((size_t)bi * S_LEN + qrow) * S_LEN + hi2 * 4;
  const float* abase = amg + (size_t)bi * S_LEN + hi2 * 4;

  // Q fragments (already scaled by log2e/8 in GEMM epilogue)
  bf16x8 qf[4];
  {
    const __hip_bfloat16* qp = qb + ((size_t)bh * S_LEN + qrow) * HDIM + hi2 * 8;
#pragma unroll
    for (int dc = 0; dc < 4; ++dc) qf[dc] = *(const bf16x8*)(qp + dc * 16);
  }

  f32x16 O[2] = {};
  float m = -INFINITY, l = 0.f;

  for (int kt = 0; kt < 16; ++kt) {
    int k0 = kt * 128;

    // struct-mask loads for the whole 128-kv step (issued early)
    u16x4 mvv[4][4];
#pragma unroll
    for (int u = 0; u < 4; ++u)
#pragma unroll
      for (int rp = 0; rp < 4; ++rp)
        mvv[u][rp] = *(const u16x4*)(mbase + k0 + u * 32 + rp * 8);

    // ---- S^T = K * Q^T, 4 sub-tiles of 32 kv rows ----
    f32x16 st[4] = {};
#pragma unroll
    for (int u = 0; u < 4; ++u) {
      const __hip_bfloat16* kp = Kb + (size_t)(k0 + u * 32 + l31) * HDIM + hi2 * 8;
#pragma unroll
      for (int dc = 0; dc < 4; ++dc) {
        bf16x8 kf = *(const bf16x8*)(kp + dc * 16);
        st[u] = __builtin_amdgcn_mfma_f32_32x32x16_bf16(kf, qf[dc], st[u], 0, 0, 0);
      }
    }

    // ---- masks + row max (lane-local, q = l31) ----
    float pmax = -3.4e38f;
#pragma unroll
    for (int u = 0; u < 4; ++u) {
#pragma unroll
      for (int rp = 0; rp < 4; ++rp) {
        float4 am = *(const float4*)(abase + k0 + u * 32 + rp * 8);
        union { u16x4 v; unsigned short e[4]; } mv;
        mv.v = mvv[u][rp];
        float s0 = fmaf(bfu2f(mv.e[0]), g2, st[u][rp * 4 + 0] + am.x);
        float s1 = fmaf(bfu2f(mv.e[1]), g2, st[u][rp * 4 + 1] + am.y);
        float s2 = fmaf(bfu2f(mv.e[2]), g2, st[u][rp * 4 + 2] + am.z);
        float s3 = fmaf(bfu2f(mv.e[3]), g2, st[u][rp * 4 + 3] + am.w);
        st[u][rp * 4 + 0] = s0; st[u][rp * 4 + 1] = s1;
        st[u][rp * 4 + 2] = s2; st[u][rp * 4 + 3] = s3;
        pmax = fmaxf(pmax, fmaxf(fmaxf(s0, s1), fmaxf(s2, s3)));
      }
    }
    pmax = fmaxf(pmax, __shfl_xor(pmax, 32));

    if (__any(pmax > m + 8.f)) {  // defer-max (T13)
      float mnew = fmaxf(m, pmax);
      float alpha = exp2f(m - mnew);
      m = mnew;
      l *= alpha;
      O[0] *= alpha;
      O[1] *= alpha;
    }

    // ---- exp2 + sum (4-way partial sums for ILP) ----
    float rs0 = 0.f, rs1 = 0.f, rs2 = 0.f, rs3 = 0.f;
#pragma unroll
    for (int u = 0; u < 4; ++u) {
#pragma unroll
      for (int rp = 0; rp < 4; ++rp) {
        float p0 = exp2f(st[u][rp * 4 + 0] - m);
        float p1 = exp2f(st[u][rp * 4 + 1] - m);
        float p2 = exp2f(st[u][rp * 4 + 2] - m);
        float p3 = exp2f(st[u][rp * 4 + 3] - m);
        st[u][rp * 4 + 0] = p0; st[u][rp * 4 + 1] = p1;
        st[u][rp * 4 + 2] = p2; st[u][rp * 4 + 3] = p3;
        rs0 += p0; rs1 += p1; rs2 += p2; rs3 += p3;
      }
    }
    float rs = (rs0 + rs1) + (rs2 + rs3);
    rs += __shfl_xor(rs, 32);
    l += rs;

    // ---- PV: O^T += V^T * P^T ; P packed via cvt_pk + permlane32_swap ----
#pragma unroll
    for (int ks = 0; ks < 8; ++ks) {
      int u = ks >> 1, rp = (ks & 1) * 2;
      unsigned A0 = cvtpk(st[u][rp * 4 + 0], st[u][rp * 4 + 1]);
      unsigned A1 = cvtpk(st[u][rp * 4 + 2], st[u][rp * 4 + 3]);
      unsigned B0 = cvtpk(st[u][rp * 4 + 4], st[u][rp * 4 + 5]);
      unsigned B1 = cvtpk(st[u][rp * 4 + 6], st[u][rp * 4 + 7]);
      asm volatile("v_permlane32_swap_b32 %0, %1" : "+v"(A0), "+v"(B0));
      asm volatile("v_permlane32_swap_b32 %0, %1" : "+v"(A1), "+v"(B1));
      union { unsigned w[4]; bf16x8 v; } Bf;
      Bf.w[0] = A0; Bf.w[1] = A1; Bf.w[2] = B0; Bf.w[3] = B1;
      const __hip_bfloat16* vp = Vb + (size_t)l31 * S_LEN + k0 + ks * 16 + hi2 * 8;
      bf16x8 v0 = *(const bf16x8*)(vp);
      bf16x8 v1 = *(const bf16x8*)(vp + 32 * S_LEN);
      O[0] = __builtin_amdgcn_mfma_f32_32x32x16_bf16(v0, Bf.v, O[0], 0, 0, 0);
      O[1] = __builtin_amdgcn_mfma_f32_32x32x16_bf16(v1, Bf.v, O[1], 0, 0, 0);
    }
  }

  // ---- epilogue: lane-local normalize, scatter stores ----
  float inv = 1.0f / l;
  float* orow = out + ((size_t)bi * S_LEN + qrow) * HIDN + h * HDIM;
#pragma unroll
  for (int dt = 0; dt < 2; ++dt)
#pragma unroll
    for (int reg = 0; reg < 16; ++reg)
      orow[dt * 32 + (reg & 3) + 8 * (reg >> 2) + 4 * hi2] = O[dt][reg] * inv;
}

extern "C" void kernel_launch(void* const* d_in, const int* in_sizes, int n_in,
                              void* d_out, int out_size, void* d_ws, size_t ws_size,
                              hipStream_t stream) {
  const float* hs    = (const float*)d_in[0];
  const float* amask = (const float*)d_in[1];
  const float* smask = (const float*)d_in[2];
  const float* Wq    = (const float*)d_in[3];
  const float* bq    = (const float*)d_in[4];
  const float* Wk    = (const float*)d_in[5];
  const float* bk    = (const float*)d_in[6];
  const float* Wv    = (const float*)d_in[7];
  const float* bv    = (const float*)d_in[8];
  const float* gate  = (const float*)d_in[9];

  char* ws = (char*)d_ws;
  __hip_bfloat16* Abf  = (__hip_bfloat16*)(ws);
  __hip_bfloat16* Wcat = (__hip_bfloat16*)(ws + 8388608);
  __hip_bfloat16* qb   = (__hip_bfloat16*)(ws + 8388608 + 6291456);
  __hip_bfloat16* kb   = qb + NA;
  __hip_bfloat16* vb   = kb + NA;
  __hip_bfloat16* Mbf  = vb + NA;
  float*          amg  = (float*)(Mbf + NM);
  __hip_bfloat16* vt   = Abf;  // alias: Abf dead after qkv_gemm

  convert_kernel<<<2048, 256, 0, stream>>>(hs, Wq, Wk, Wv, smask, amask, Abf, Wcat, Mbf, amg);
  qkv_gemm<<<768, 256, 0, stream>>>(Abf, Wcat, bq, bk, bv, qb, kb, vb);
  vtrans_kernel<<<1024, 256, 0, stream>>>(vb, vt);
  attn_kernel<<<512, 256, 0, stream>>>(qb, kb, vt, Mbf, amg, gate, (float*)d_out);
}

// Round 4
// 185.041 us; speedup vs baseline: 1.3310x; 1.3310x over previous
//
#include <hip/hip_runtime.h>
#include <hip/hip_bf16.h>
#include <cmath>

// Problem constants
#define S_LEN 2048
#define HIDN  1024
#define NHEAD 16
#define HDIM  64
#define NBAT  2

static constexpr long NA = (long)NBAT * S_LEN * HIDN;  // hidden elems
static constexpr long NW = (long)HIDN * HIDN;          // per weight
static constexpr long NM = (long)NBAT * S_LEN * S_LEN; // struct mask elems
static constexpr long NAM = (long)NBAT * S_LEN;        // amask elems

typedef __attribute__((ext_vector_type(8))) __bf16 bf16x8;
typedef __attribute__((ext_vector_type(4))) float f32x4;
typedef __attribute__((ext_vector_type(16))) float f32x16;
typedef __attribute__((ext_vector_type(4))) unsigned short u16x4;

#define LOG2E 1.44269504088896340736f

__device__ __forceinline__ unsigned short f2bf(float f) {
  __hip_bfloat16 h = __float2bfloat16(f);
  unsigned short u;
  __builtin_memcpy(&u, &h, 2);
  return u;
}

__device__ __forceinline__ float bfu2f(unsigned short u) {
  unsigned v = (unsigned)u << 16;
  float f;
  __builtin_memcpy(&f, &v, 4);
  return f;
}

// packed f32->bf16 RNE: low16 = bf16(a), high16 = bf16(b); 1 instr
__device__ __forceinline__ unsigned cvtpk(float a, float b) {
  unsigned r;
  asm volatile("v_cvt_pk_bf16_f32 %0, %1, %2" : "=v"(r) : "v"(a), "v"(b));
  return r;
}

__device__ __forceinline__ void gload_lds16(const void* g, void* l) {
  __builtin_amdgcn_global_load_lds(
      (const __attribute__((address_space(1))) void*)g,
      (__attribute__((address_space(3))) void*)l, 16, 0, 0);
}

// ---------------- kernel 1: fp32 -> bf16 conversions (+ amask prescale) ----------------
__global__ __launch_bounds__(256) void convert_kernel(
    const float* __restrict__ hs, const float* __restrict__ wq,
    const float* __restrict__ wk, const float* __restrict__ wv,
    const float* __restrict__ mask, const float* __restrict__ amask,
    __hip_bfloat16* __restrict__ Abf, __hip_bfloat16* __restrict__ Wcat,
    __hip_bfloat16* __restrict__ Mbf, float* __restrict__ amg) {
  const long tot4 = (NA + 3 * NW + NM + NAM) >> 2;
  for (long i4 = (long)blockIdx.x * blockDim.x + threadIdx.x; i4 < tot4;
       i4 += (long)gridDim.x * blockDim.x) {
    long i = i4 << 2;
    if (i < NA + 3 * NW + NM) {
      const float* s;
      __hip_bfloat16* dq;
      if (i < NA)               { s = hs + i;                   dq = Abf + i; }
      else if (i < NA + NW)     { s = wq + (i - NA);            dq = Wcat + (i - NA); }
      else if (i < NA + 2 * NW) { s = wk + (i - NA - NW);       dq = Wcat + (i - NA); }
      else if (i < NA + 3 * NW) { s = wv + (i - NA - 2 * NW);   dq = Wcat + (i - NA); }
      else                      { s = mask + (i - NA - 3 * NW); dq = Mbf + (i - NA - 3 * NW); }
      float4 v = *(const float4*)s;
      union { unsigned short u[4]; uint2 p; } o;
      o.u[0] = f2bf(v.x); o.u[1] = f2bf(v.y); o.u[2] = f2bf(v.z); o.u[3] = f2bf(v.w);
      *(uint2*)dq = o.p;
    } else {
      long j = i - (NA + 3 * NW + NM);
      float4 v = *(const float4*)(amask + j);
      v.x *= LOG2E; v.y *= LOG2E; v.z *= LOG2E; v.w *= LOG2E;
      *(float4*)(amg + j) = v;
    }
  }
}

// ---------------- kernel 2: QKV GEMM (m97 structure) ----------------
// q output pre-scaled by c2 = log2(e)/sqrt(HD) so attn scores are log2-domain
__global__ __launch_bounds__(256) void qkv_gemm(
    const __hip_bfloat16* __restrict__ A, const __hip_bfloat16* __restrict__ Bw,
    const float* __restrict__ bq, const float* __restrict__ bk,
    const float* __restrict__ bv, __hip_bfloat16* __restrict__ qb,
    __hip_bfloat16* __restrict__ kb, __hip_bfloat16* __restrict__ vb) {
  __shared__ __hip_bfloat16 sA[128 * 32];
  __shared__ __hip_bfloat16 sB[128 * 32];

  int bid = blockIdx.x;
  int cpx = gridDim.x >> 3;
  int wg = (bid & 7) * cpx + (bid >> 3);
  int bm = wg / 24, bn = wg % 24;
  int tid = threadIdx.x, lane = tid & 63, wid = tid >> 6;
  int wr = wid >> 1, wc = wid & 1;
  int lr = lane & 15, hi = lane >> 4;
  int srow = lane >> 2, scol = (lane & 3) * 8;

  f32x4 acc[4][4] = {};

  for (int kt = 0; kt < 32; ++kt) {
    int k0 = kt * 32;
#pragma unroll
    for (int cc = 0; cc < 2; ++cc) {
      int c = wid * 2 + cc;
      const __hip_bfloat16* ga =
          A + ((size_t)(bm * 128 + c * 16 + srow) * 1024 + k0 + scol);
      gload_lds16(ga, (char*)sA + c * 1024);
      const __hip_bfloat16* gb =
          Bw + ((size_t)(bn * 128 + c * 16 + srow) * 1024 + k0 + scol);
      gload_lds16(gb, (char*)sB + c * 1024);
    }
    __syncthreads();
    bf16x8 af[4], bf[4];
#pragma unroll
    for (int mt = 0; mt < 4; ++mt)
      af[mt] = *(const bf16x8*)((const char*)sA +
                                ((wr * 64 + mt * 16 + lr) * 32 + hi * 8) * 2);
#pragma unroll
    for (int nt = 0; nt < 4; ++nt)
      bf[nt] = *(const bf16x8*)((const char*)sB +
                                ((wc * 64 + nt * 16 + lr) * 32 + hi * 8) * 2);
#pragma unroll
    for (int mt = 0; mt < 4; ++mt)
#pragma unroll
      for (int nt = 0; nt < 4; ++nt)
        acc[mt][nt] =
            __builtin_amdgcn_mfma_f32_16x16x32_bf16(af[mt], bf[nt], acc[mt][nt], 0, 0, 0);
    __syncthreads();
  }

  const float c2 = LOG2E / 8.0f;
#pragma unroll
  for (int nt = 0; nt < 4; ++nt) {
    int nb = bn * 128 + wc * 64 + nt * 16;
    int t = nb >> 10;
    int rem = nb & 1023;
    const float* bp = (t == 0) ? bq : (t == 1) ? bk : bv;
    __hip_bfloat16* ob = (t == 0) ? qb : (t == 1) ? kb : vb;
    float scl = (t == 0) ? c2 : 1.0f;
    int h = rem >> 6, d0 = rem & 63;
    float bias = bp[rem + lr];
    int d = d0 + lr;
#pragma unroll
    for (int mt = 0; mt < 4; ++mt) {
#pragma unroll
      for (int r = 0; r < 4; ++r) {
        int m = bm * 128 + wr * 64 + mt * 16 + hi * 4 + r;
        int b = m >> 11, s = m & 2047;
        size_t off = (((size_t)(b * NHEAD + h)) * S_LEN + s) * HDIM + d;
        ob[off] = __float2bfloat16((acc[mt][nt][r] + bias) * scl);
      }
    }
  }
}

// ---------------- kernel 3: V -> V^T  ([bh][s][d] -> [bh][d][s]) ----------------
__global__ __launch_bounds__(256) void vtrans_kernel(
    const __hip_bfloat16* __restrict__ vb, __hip_bfloat16* __restrict__ vt) {
  __shared__ __hip_bfloat16 tile[64][72];
  int bh = blockIdx.x >> 5;
  int st = blockIdx.x & 31;
  int t = threadIdx.x;
  int r8 = t >> 3, c8 = (t & 7) * 8;
#pragma unroll
  for (int p = 0; p < 2; ++p) {
    int row = p * 32 + r8;
    bf16x8 v = *(const bf16x8*)(vb + ((size_t)bh * S_LEN + st * 64 + row) * HDIM + c8);
    *(bf16x8*)&tile[row][c8] = v;
  }
  __syncthreads();
#pragma unroll
  for (int p = 0; p < 2; ++p) {
    int d = p * 32 + r8;
    union { unsigned short u[8]; bf16x8 v; } o;
#pragma unroll
    for (int j = 0; j < 8; ++j) {
      __hip_bfloat16 e = tile[c8 + j][d];
      __builtin_memcpy(&o.u[j], &e, 2);
    }
    *(bf16x8*)(vt + ((size_t)bh * HDIM + d) * S_LEN + st * 64 + c8) = o.v;
  }
}

// ---------------- kernel 4: KV-split flash attention, swapped-QK^T ----------------
// 512 blocks x 512 threads (8 waves). Waves 0-3: KV rows 0-1023; waves 4-7: 1024-2047.
// Each group: double-buffered K/V^T LDS staging (global_load_lds, XOR-swizzled).
// End: group 1 dumps (m,l,O^T) to LDS; group 0 merges (online-softmax combine) + stores.
__global__ __launch_bounds__(512, 4) void attn_kernel(
    const __hip_bfloat16* __restrict__ qb, const __hip_bfloat16* __restrict__ kbuf,
    const __hip_bfloat16* __restrict__ vt, const __hip_bfloat16* __restrict__ Mbf,
    const float* __restrict__ amg, const float* __restrict__ gate,
    float* __restrict__ out) {
  __shared__ alignas(16) char smem[65536];  // [grp][buf][K|V][8192]; merge aliases
  __shared__ float mlb[4][2][32];

  int bid = blockIdx.x;
  int wg = (bid & 7) * 64 + (bid >> 3);  // XCD swizzle: 64 consecutive wg per XCD
  int bi = wg >> 8;
  int h = (wg >> 4) & 15;   // h slow-ish: one XCD holds 4 heads' K/V in its L2
  int qt = wg & 15;
  int bh = bi * NHEAD + h;

  int tid = threadIdx.x;
  int lane = tid & 63, wid = tid >> 6;
  int grp = wid >> 2, w4 = wid & 3;
  int l31 = lane & 31, hi2 = lane >> 5;
  int qrow = qt * 128 + w4 * 32 + l31;
  int kbase = grp << 10;
  float g2 = gate[h] * LOG2E;

  const char* Kb = (const char*)kbuf + (size_t)bh * S_LEN * 128;
  const char* Vb = (const char*)vt + (size_t)bh * HDIM * S_LEN * 2;
  const unsigned short* mbase =
      (const unsigned short*)Mbf + ((size_t)bi * S_LEN + qrow) * S_LEN + hi2 * 4;
  const float* abase = amg + (size_t)bi * S_LEN + hi2 * 4;

  // Q fragments (pre-scaled by log2e/8 in GEMM epilogue)
  bf16x8 qf[4];
  {
    const __hip_bfloat16* qp = qb + ((size_t)bh * S_LEN + qrow) * HDIM + hi2 * 8;
#pragma unroll
    for (int dc = 0; dc < 4; ++dc) qf[dc] = *(const bf16x8*)(qp + dc * 16);
  }

  int r8 = lane >> 3, col16 = lane & 7;
  int swzc = (col16 ^ r8) << 4;   // pre-swizzled global source column (rule 21)
  int rswz = (l31 & 7) << 4;      // matching read-side XOR
  char* sbase = smem + grp * 32768;

  auto stage = [&](int buf, int t) {
    int k0 = kbase + t * 64;
#pragma unroll
    for (int cc = 0; cc < 2; ++cc) {
      int ch = w4 * 2 + cc;
      int row = ch * 8 + r8;
      gload_lds16(Kb + (size_t)(k0 + row) * 128 + swzc,
                  sbase + buf * 16384 + ch * 1024);
      gload_lds16(Vb + (size_t)row * 4096 + (size_t)k0 * 2 + swzc,
                  sbase + buf * 16384 + 8192 + ch * 1024);
    }
  };

  f32x16 O[2] = {};
  float m = -INFINITY, l = 0.f;

  stage(0, 0);
  __syncthreads();

  for (int kt = 0; kt < 16; ++kt) {
    int cur = kt & 1;
    if (kt < 15) stage(cur ^ 1, kt + 1);  // into other buffer; drained by end barrier
    int k0 = kbase + kt * 64;

    // struct-mask loads issued early (consumed after QK^T)
    u16x4 mvv[2][4];
#pragma unroll
    for (int kb2 = 0; kb2 < 2; ++kb2)
#pragma unroll
      for (int rp = 0; rp < 4; ++rp)
        mvv[kb2][rp] = *(const u16x4*)(mbase + k0 + kb2 * 32 + rp * 8);

    const char* sKc = sbase + cur * 16384;
    const char* sVc = sKc + 8192;

    // ---- S^T = K * Q^T ----
    f32x16 st[2] = {};
    __builtin_amdgcn_s_setprio(1);
#pragma unroll
    for (int kb2 = 0; kb2 < 2; ++kb2) {
      int row = kb2 * 32 + l31;
#pragma unroll
      for (int dc = 0; dc < 4; ++dc) {
        bf16x8 kf = *(const bf16x8*)(sKc + row * 128 + ((dc * 32 + hi2 * 16) ^ rswz));
        st[kb2] = __builtin_amdgcn_mfma_f32_32x32x16_bf16(kf, qf[dc], st[kb2], 0, 0, 0);
      }
    }
    __builtin_amdgcn_s_setprio(0);

    // ---- masks + row max (lane-local, q = l31) ----
    float pmax = -3.4e38f;
#pragma unroll
    for (int kb2 = 0; kb2 < 2; ++kb2) {
#pragma unroll
      for (int rp = 0; rp < 4; ++rp) {
        float4 am = *(const float4*)(abase + k0 + kb2 * 32 + rp * 8);
        union { u16x4 v; unsigned short e[4]; } mv;
        mv.v = mvv[kb2][rp];
        float s0 = fmaf(bfu2f(mv.e[0]), g2, st[kb2][rp * 4 + 0] + am.x);
        float s1 = fmaf(bfu2f(mv.e[1]), g2, st[kb2][rp * 4 + 1] + am.y);
        float s2 = fmaf(bfu2f(mv.e[2]), g2, st[kb2][rp * 4 + 2] + am.z);
        float s3 = fmaf(bfu2f(mv.e[3]), g2, st[kb2][rp * 4 + 3] + am.w);
        st[kb2][rp * 4 + 0] = s0; st[kb2][rp * 4 + 1] = s1;
        st[kb2][rp * 4 + 2] = s2; st[kb2][rp * 4 + 3] = s3;
        pmax = fmaxf(pmax, fmaxf(fmaxf(s0, s1), fmaxf(s2, s3)));
      }
    }
    pmax = fmaxf(pmax, __shfl_xor(pmax, 32));

    if (__any(pmax > m + 8.f)) {  // defer-max (T13)
      float mnew = fmaxf(m, pmax);
      float alpha = exp2f(m - mnew);
      m = mnew;
      l *= alpha;
      O[0] *= alpha;
      O[1] *= alpha;
    }

    // ---- exp2 + sum ----
    float rs0 = 0.f, rs1 = 0.f, rs2 = 0.f, rs3 = 0.f;
#pragma unroll
    for (int kb2 = 0; kb2 < 2; ++kb2) {
#pragma unroll
      for (int rp = 0; rp < 4; ++rp) {
        float p0 = exp2f(st[kb2][rp * 4 + 0] - m);
        float p1 = exp2f(st[kb2][rp * 4 + 1] - m);
        float p2 = exp2f(st[kb2][rp * 4 + 2] - m);
        float p3 = exp2f(st[kb2][rp * 4 + 3] - m);
        st[kb2][rp * 4 + 0] = p0; st[kb2][rp * 4 + 1] = p1;
        st[kb2][rp * 4 + 2] = p2; st[kb2][rp * 4 + 3] = p3;
        rs0 += p0; rs1 += p1; rs2 += p2; rs3 += p3;
      }
    }
    float rs = (rs0 + rs1) + (rs2 + rs3);
    rs += __shfl_xor(rs, 32);
    l += rs;

    // ---- PV: O^T += V^T * P^T (cvt_pk + permlane32_swap pack) ----
    __builtin_amdgcn_s_setprio(1);
#pragma unroll
    for (int ks = 0; ks < 4; ++ks) {
      int kb2 = ks >> 1, rp = (ks & 1) * 2;
      unsigned A0 = cvtpk(st[kb2][rp * 4 + 0], st[kb2][rp * 4 + 1]);
      unsigned A1 = cvtpk(st[kb2][rp * 4 + 2], st[kb2][rp * 4 + 3]);
      unsigned B0 = cvtpk(st[kb2][rp * 4 + 4], st[kb2][rp * 4 + 5]);
      unsigned B1 = cvtpk(st[kb2][rp * 4 + 6], st[kb2][rp * 4 + 7]);
      asm volatile("v_permlane32_swap_b32 %0, %1" : "+v"(A0), "+v"(B0));
      asm volatile("v_permlane32_swap_b32 %0, %1" : "+v"(A1), "+v"(B1));
      union { unsigned w[4]; bf16x8 v; } Bf;
      Bf.w[0] = A0; Bf.w[1] = A1; Bf.w[2] = B0; Bf.w[3] = B1;
#pragma unroll
      for (int dt = 0; dt < 2; ++dt) {
        int row = dt * 32 + l31;
        bf16x8 vf = *(const bf16x8*)(sVc + row * 128 + ((ks * 32 + hi2 * 16) ^ rswz));
        O[dt] = __builtin_amdgcn_mfma_f32_32x32x16_bf16(vf, Bf.v, O[dt], 0, 0, 0);
      }
    }
    __builtin_amdgcn_s_setprio(0);
    __syncthreads();  // readers done; drains next-tile stage
  }

  // ---- merge the two KV halves (group 1 -> LDS, group 0 combines + stores) ----
  float* mbuf = (float*)smem + w4 * (32 * 68);  // [q 32][d 68-padded] per wave-pair
  if (grp == 1) {
    if (hi2 == 0) { mlb[w4][0][l31] = m; mlb[w4][1][l31] = l; }
#pragma unroll
    for (int dt = 0; dt < 2; ++dt)
#pragma unroll
      for (int rq = 0; rq < 4; ++rq) {
        int d0 = dt * 32 + 8 * rq + 4 * hi2;
        f32x4 v = {O[dt][rq * 4 + 0], O[dt][rq * 4 + 1],
                   O[dt][rq * 4 + 2], O[dt][rq * 4 + 3]};
        *(f32x4*)(mbuf + l31 * 68 + d0) = v;
      }
  }
  __syncthreads();
  if (grp == 0) {
    float m1 = mlb[w4][0][l31], l1 = mlb[w4][1][l31];
    float mx = fmaxf(m, m1);
    float a0 = exp2f(m - mx), a1 = exp2f(m1 - mx);
    float linv = 1.0f / (a0 * l + a1 * l1);
    a0 *= linv; a1 *= linv;
    float* orow = out + ((size_t)bi * S_LEN + qrow) * HIDN + h * HDIM;
#pragma unroll
    for (int dt = 0; dt < 2; ++dt)
#pragma unroll
      for (int rq = 0; rq < 4; ++rq) {
        int d0 = dt * 32 + 8 * rq + 4 * hi2;
        f32x4 v1 = *(const f32x4*)(mbuf + l31 * 68 + d0);
        float4 o;
        o.x = O[dt][rq * 4 + 0] * a0 + v1[0] * a1;
        o.y = O[dt][rq * 4 + 1] * a0 + v1[1] * a1;
        o.z = O[dt][rq * 4 + 2] * a0 + v1[2] * a1;
        o.w = O[dt][rq * 4 + 3] * a0 + v1[3] * a1;
        *(float4*)(orow + d0) = o;
      }
  }
}

extern "C" void kernel_launch(void* const* d_in, const int* in_sizes, int n_in,
                              void* d_out, int out_size, void* d_ws, size_t ws_size,
                              hipStream_t stream) {
  const float* hs    = (const float*)d_in[0];
  const float* amask = (const float*)d_in[1];
  const float* smask = (const float*)d_in[2];
  const float* Wq    = (const float*)d_in[3];
  const float* bq    = (const float*)d_in[4];
  const float* Wk    = (const float*)d_in[5];
  const float* bk    = (const float*)d_in[6];
  const float* Wv    = (const float*)d_in[7];
  const float* bv    = (const float*)d_in[8];
  const float* gate  = (const float*)d_in[9];

  char* ws = (char*)d_ws;
  __hip_bfloat16* Abf  = (__hip_bfloat16*)(ws);
  __hip_bfloat16* Wcat = (__hip_bfloat16*)(ws + 8388608);
  __hip_bfloat16* qb   = (__hip_bfloat16*)(ws + 8388608 + 6291456);
  __hip_bfloat16* kb   = qb + NA;
  __hip_bfloat16* vb   = kb + NA;
  __hip_bfloat16* Mbf  = vb + NA;
  float*          amg  = (float*)(Mbf + NM);
  __hip_bfloat16* vt   = Abf;  // alias: Abf dead after qkv_gemm

  convert_kernel<<<2048, 256, 0, stream>>>(hs, Wq, Wk, Wv, smask, amask, Abf, Wcat, Mbf, amg);
  qkv_gemm<<<768, 256, 0, stream>>>(Abf, Wcat, bq, bk, bv, qb, kb, vb);
  vtrans_kernel<<<1024, 256, 0, stream>>>(vb, vt);
  attn_kernel<<<512, 512, 0, stream>>>(qb, kb, vt, Mbf, amg, gate, (float*)d_out);
}

// Round 5
// 150.815 us; speedup vs baseline: 1.6330x; 1.2269x over previous
//
#include <hip/hip_runtime.h>
#include <hip/hip_bf16.h>
#include <cmath>

// Problem constants
#define S_LEN 2048
#define HIDN  1024
#define NHEAD 16
#define HDIM  64
#define NBAT  2

static constexpr long NA = (long)NBAT * S_LEN * HIDN;  // hidden elems
static constexpr long NW = (long)HIDN * HIDN;          // per weight
static constexpr long NM = (long)NBAT * S_LEN * S_LEN; // struct mask elems
static constexpr long NAM = (long)NBAT * S_LEN;        // amask elems

typedef __attribute__((ext_vector_type(8))) __bf16 bf16x8;
typedef __attribute__((ext_vector_type(4))) float f32x4;
typedef __attribute__((ext_vector_type(16))) float f32x16;
typedef __attribute__((ext_vector_type(4))) unsigned short u16x4;

#define LOG2E 1.44269504088896340736f

__device__ __forceinline__ unsigned short f2bf(float f) {
  __hip_bfloat16 h = __float2bfloat16(f);
  unsigned short u;
  __builtin_memcpy(&u, &h, 2);
  return u;
}

__device__ __forceinline__ float bfu2f(unsigned short u) {
  unsigned v = (unsigned)u << 16;
  float f;
  __builtin_memcpy(&f, &v, 4);
  return f;
}

// packed f32->bf16 RNE: low16 = bf16(a), high16 = bf16(b); 1 instr
__device__ __forceinline__ unsigned cvtpk(float a, float b) {
  unsigned r;
  asm volatile("v_cvt_pk_bf16_f32 %0, %1, %2" : "=v"(r) : "v"(a), "v"(b));
  return r;
}

__device__ __forceinline__ void gload_lds16(const void* g, void* l) {
  __builtin_amdgcn_global_load_lds(
      (const __attribute__((address_space(1))) void*)g,
      (__attribute__((address_space(3))) void*)l, 16, 0, 0);
}

// ---------------- kernel 1: fp32 -> bf16 conversions (+ amask prescale) ----------------
__global__ __launch_bounds__(256) void convert_kernel(
    const float* __restrict__ hs, const float* __restrict__ wq,
    const float* __restrict__ wk, const float* __restrict__ wv,
    const float* __restrict__ mask, const float* __restrict__ amask,
    __hip_bfloat16* __restrict__ Abf, __hip_bfloat16* __restrict__ Wcat,
    __hip_bfloat16* __restrict__ Mbf, float* __restrict__ amg) {
  const long tot4 = (NA + 3 * NW + NM + NAM) >> 2;
  for (long i4 = (long)blockIdx.x * blockDim.x + threadIdx.x; i4 < tot4;
       i4 += (long)gridDim.x * blockDim.x) {
    long i = i4 << 2;
    if (i < NA + 3 * NW + NM) {
      const float* s;
      __hip_bfloat16* dq;
      if (i < NA)               { s = hs + i;                   dq = Abf + i; }
      else if (i < NA + NW)     { s = wq + (i - NA);            dq = Wcat + (i - NA); }
      else if (i < NA + 2 * NW) { s = wk + (i - NA - NW);       dq = Wcat + (i - NA); }
      else if (i < NA + 3 * NW) { s = wv + (i - NA - 2 * NW);   dq = Wcat + (i - NA); }
      else                      { s = mask + (i - NA - 3 * NW); dq = Mbf + (i - NA - 3 * NW); }
      float4 v = *(const float4*)s;
      union { unsigned short u[4]; uint2 p; } o;
      o.u[0] = f2bf(v.x); o.u[1] = f2bf(v.y); o.u[2] = f2bf(v.z); o.u[3] = f2bf(v.w);
      *(uint2*)dq = o.p;
    } else {
      long j = i - (NA + 3 * NW + NM);
      float4 v = *(const float4*)(amask + j);
      v.x *= LOG2E; v.y *= LOG2E; v.z *= LOG2E; v.w *= LOG2E;
      *(float4*)(amg + j) = v;
    }
  }
}

// ---------------- kernel 2: QKV GEMM (m97 structure) ----------------
// q output pre-scaled by c2 = log2(e)/sqrt(HD) so attn scores are log2-domain
__global__ __launch_bounds__(256) void qkv_gemm(
    const __hip_bfloat16* __restrict__ A, const __hip_bfloat16* __restrict__ Bw,
    const float* __restrict__ bq, const float* __restrict__ bk,
    const float* __restrict__ bv, __hip_bfloat16* __restrict__ qb,
    __hip_bfloat16* __restrict__ kb, __hip_bfloat16* __restrict__ vb) {
  __shared__ __hip_bfloat16 sA[128 * 32];
  __shared__ __hip_bfloat16 sB[128 * 32];

  int bid = blockIdx.x;
  int cpx = gridDim.x >> 3;
  int wg = (bid & 7) * cpx + (bid >> 3);
  int bm = wg / 24, bn = wg % 24;
  int tid = threadIdx.x, lane = tid & 63, wid = tid >> 6;
  int wr = wid >> 1, wc = wid & 1;
  int lr = lane & 15, hi = lane >> 4;
  int srow = lane >> 2, scol = (lane & 3) * 8;

  f32x4 acc[4][4] = {};

  for (int kt = 0; kt < 32; ++kt) {
    int k0 = kt * 32;
#pragma unroll
    for (int cc = 0; cc < 2; ++cc) {
      int c = wid * 2 + cc;
      const __hip_bfloat16* ga =
          A + ((size_t)(bm * 128 + c * 16 + srow) * 1024 + k0 + scol);
      gload_lds16(ga, (char*)sA + c * 1024);
      const __hip_bfloat16* gb =
          Bw + ((size_t)(bn * 128 + c * 16 + srow) * 1024 + k0 + scol);
      gload_lds16(gb, (char*)sB + c * 1024);
    }
    __syncthreads();
    bf16x8 af[4], bf[4];
#pragma unroll
    for (int mt = 0; mt < 4; ++mt)
      af[mt] = *(const bf16x8*)((const char*)sA +
                                ((wr * 64 + mt * 16 + lr) * 32 + hi * 8) * 2);
#pragma unroll
    for (int nt = 0; nt < 4; ++nt)
      bf[nt] = *(const bf16x8*)((const char*)sB +
                                ((wc * 64 + nt * 16 + lr) * 32 + hi * 8) * 2);
#pragma unroll
    for (int mt = 0; mt < 4; ++mt)
#pragma unroll
      for (int nt = 0; nt < 4; ++nt)
        acc[mt][nt] =
            __builtin_amdgcn_mfma_f32_16x16x32_bf16(af[mt], bf[nt], acc[mt][nt], 0, 0, 0);
    __syncthreads();
  }

  const float c2 = LOG2E / 8.0f;
#pragma unroll
  for (int nt = 0; nt < 4; ++nt) {
    int nb = bn * 128 + wc * 64 + nt * 16;
    int t = nb >> 10;
    int rem = nb & 1023;
    const float* bp = (t == 0) ? bq : (t == 1) ? bk : bv;
    __hip_bfloat16* ob = (t == 0) ? qb : (t == 1) ? kb : vb;
    float scl = (t == 0) ? c2 : 1.0f;
    int h = rem >> 6, d0 = rem & 63;
    float bias = bp[rem + lr];
    int d = d0 + lr;
#pragma unroll
    for (int mt = 0; mt < 4; ++mt) {
#pragma unroll
      for (int r = 0; r < 4; ++r) {
        int m = bm * 128 + wr * 64 + mt * 16 + hi * 4 + r;
        int b = m >> 11, s = m & 2047;
        size_t off = (((size_t)(b * NHEAD + h)) * S_LEN + s) * HDIM + d;
        ob[off] = __float2bfloat16((acc[mt][nt][r] + bias) * scl);
      }
    }
  }
}

// ---------------- kernel 3: V -> V^T  ([bh][s][d] -> [bh][d][s]) ----------------
__global__ __launch_bounds__(256) void vtrans_kernel(
    const __hip_bfloat16* __restrict__ vb, __hip_bfloat16* __restrict__ vt) {
  __shared__ __hip_bfloat16 tile[64][72];
  int bh = blockIdx.x >> 5;
  int st = blockIdx.x & 31;
  int t = threadIdx.x;
  int r8 = t >> 3, c8 = (t & 7) * 8;
#pragma unroll
  for (int p = 0; p < 2; ++p) {
    int row = p * 32 + r8;
    bf16x8 v = *(const bf16x8*)(vb + ((size_t)bh * S_LEN + st * 64 + row) * HDIM + c8);
    *(bf16x8*)&tile[row][c8] = v;
  }
  __syncthreads();
#pragma unroll
  for (int p = 0; p < 2; ++p) {
    int d = p * 32 + r8;
    union { unsigned short u[8]; bf16x8 v; } o;
#pragma unroll
    for (int j = 0; j < 8; ++j) {
      __hip_bfloat16 e = tile[c8 + j][d];
      __builtin_memcpy(&o.u[j], &e, 2);
    }
    *(bf16x8*)(vt + ((size_t)bh * HDIM + d) * S_LEN + st * 64 + c8) = o.v;
  }
}

// ---------------- kernel 4: KV-split flash attention, swapped-QK^T ----------------
// 512 blocks x 512 threads (8 waves). Waves 0-3: KV rows 0-1023; waves 4-7: 1024-2047.
// KVBLK=32; K, V^T, AND struct-mask all staged via global_load_lds (double-buffered,
// pre-swizzled source cols + XOR read). Merge of the two halves through LDS at the end.
__global__ __launch_bounds__(512, 4) void attn_kernel(
    const __hip_bfloat16* __restrict__ qb, const __hip_bfloat16* __restrict__ kbuf,
    const __hip_bfloat16* __restrict__ vt, const __hip_bfloat16* __restrict__ Mbf,
    const float* __restrict__ amg, const float* __restrict__ gate,
    float* __restrict__ out) {
  // [0,32768): KV staging [buf2][grp2][K 4KB | V 4KB]
  // [32768,65536): mask staging [buf2][wave8][2KB]
  __shared__ alignas(16) char smem[65536];
  __shared__ float mlb[4][2][32];

  int bid = blockIdx.x;
  int wg = (bid & 7) * 64 + (bid >> 3);  // XCD swizzle (bijective, 512 = 8*64)
  int bi = wg >> 8;
  int h = (wg >> 4) & 15;  // 4 heads' K/V per XCD -> L2-resident
  int qt = wg & 15;
  int bh = bi * NHEAD + h;

  int tid = threadIdx.x;
  int lane = tid & 63, wid = tid >> 6;
  int grp = wid >> 2, w4 = wid & 3;
  int l31 = lane & 31, hi2 = lane >> 5;
  int qbase = qt * 128 + w4 * 32;
  int qrow = qbase + l31;
  int kbase = grp << 10;
  float g2 = gate[h] * LOG2E;

  const char* Kb = (const char*)kbuf + (size_t)bh * S_LEN * 128;
  const char* Vb = (const char*)vt + (size_t)bh * HDIM * S_LEN * 2;
  const char* Mq = (const char*)Mbf + ((size_t)bi * S_LEN + qbase) * S_LEN * 2;
  const float* abase = amg + (size_t)bi * S_LEN + hi2 * 4;

  // Q fragments (pre-scaled by log2e/8 in GEMM epilogue)
  bf16x8 qf[4];
  {
    const __hip_bfloat16* qp = qb + ((size_t)bh * S_LEN + qrow) * HDIM + hi2 * 8;
#pragma unroll
    for (int dc = 0; dc < 4; ++dc) qf[dc] = *(const bf16x8*)(qp + dc * 16);
  }

  int r8 = lane >> 3;
  int swzK = ((lane & 7) ^ r8) << 4;               // K source swizzle (rows of 128B)
  int r4 = lane >> 2;
  int swz64 = ((lane & 3) ^ (r4 & 3)) << 4;        // V/mask source swizzle (rows of 64B)

  auto stage = [&](int buf, int t) {
    int k0 = kbase + t * 32;
    char* base = smem + buf * 8192 + grp * 4096 + w4 * 1024;
    // K: rows k0 + w4*8 + r8, 128B each (1 KB per wave)
    gload_lds16(Kb + (size_t)(k0 + w4 * 8 + r8) * 128 + swzK, base);
    // V^T: rows d = w4*16 + r4, 64B slice at k0 (1 KB per wave)
    gload_lds16(Vb + (size_t)(w4 * 16 + r4) * 4096 + (size_t)k0 * 2 + swz64,
                base + 16384);
    // struct mask: wave's 32 q-rows x 32 keys (2 KB per wave, 2 instrs)
    char* mdst = smem + 32768 + buf * 16384 + wid * 2048;
#pragma unroll
    for (int c = 0; c < 2; ++c) {
      int mrow = c * 16 + r4;
      gload_lds16(Mq + (size_t)mrow * 4096 + (size_t)k0 * 2 + swz64,
                  mdst + c * 1024);
    }
  };

  f32x16 O = {};  // d-rows 0..31 for dt slice; second half in O2
  f32x16 O2 = {};
  float m = -INFINITY, l = 0.f;
  int rswzK = (l31 & 7) << 4;
  int rswz64 = (l31 & 3) << 4;

  stage(0, 0);
  __syncthreads();

  for (int kt = 0; kt < 32; ++kt) {
    int cur = kt & 1;
    if (kt < 31) stage(cur ^ 1, kt + 1);
    int k0 = kbase + kt * 32;

    const char* sKc = smem + cur * 8192 + grp * 4096;
    const char* sVc = sKc + 16384;
    const char* sMc = smem + 32768 + cur * 16384 + wid * 2048;

    // ---- S^T = K * Q^T (one 32-key subtile) ----
    f32x16 st = {};
#pragma unroll
    for (int dc = 0; dc < 4; ++dc) {
      bf16x8 kf = *(const bf16x8*)(sKc + l31 * 128 + ((dc * 32 + hi2 * 16) ^ rswzK));
      st = __builtin_amdgcn_mfma_f32_32x32x16_bf16(kf, qf[dc], st, 0, 0, 0);
    }

    // ---- masks + row max (lane-local, q = l31) ----
    float pmax = -3.4e38f;
#pragma unroll
    for (int rp = 0; rp < 4; ++rp) {
      float4 am = *(const float4*)(abase + k0 + rp * 8);
      union { u16x4 v; unsigned short e[4]; } mv;
      mv.v = *(const u16x4*)(sMc + l31 * 64 + ((rp * 16) ^ rswz64) + hi2 * 8);
      float s0 = fmaf(bfu2f(mv.e[0]), g2, st[rp * 4 + 0] + am.x);
      float s1 = fmaf(bfu2f(mv.e[1]), g2, st[rp * 4 + 1] + am.y);
      float s2 = fmaf(bfu2f(mv.e[2]), g2, st[rp * 4 + 2] + am.z);
      float s3 = fmaf(bfu2f(mv.e[3]), g2, st[rp * 4 + 3] + am.w);
      st[rp * 4 + 0] = s0; st[rp * 4 + 1] = s1;
      st[rp * 4 + 2] = s2; st[rp * 4 + 3] = s3;
      pmax = fmaxf(pmax, fmaxf(fmaxf(s0, s1), fmaxf(s2, s3)));
    }
    pmax = fmaxf(pmax, __shfl_xor(pmax, 32));

    if (__any(pmax > m + 8.f)) {  // defer-max (T13)
      float mnew = fmaxf(m, pmax);
      float alpha = exp2f(m - mnew);
      m = mnew;
      l *= alpha;
      O *= alpha;
      O2 *= alpha;
    }

    // ---- exp2 + sum ----
    float rs0 = 0.f, rs1 = 0.f, rs2 = 0.f, rs3 = 0.f;
#pragma unroll
    for (int rp = 0; rp < 4; ++rp) {
      float p0 = exp2f(st[rp * 4 + 0] - m);
      float p1 = exp2f(st[rp * 4 + 1] - m);
      float p2 = exp2f(st[rp * 4 + 2] - m);
      float p3 = exp2f(st[rp * 4 + 3] - m);
      st[rp * 4 + 0] = p0; st[rp * 4 + 1] = p1;
      st[rp * 4 + 2] = p2; st[rp * 4 + 3] = p3;
      rs0 += p0; rs1 += p1; rs2 += p2; rs3 += p3;
    }
    float rs = (rs0 + rs1) + (rs2 + rs3);
    rs += __shfl_xor(rs, 32);
    l += rs;

    // ---- PV: O^T += V^T * P^T (cvt_pk + permlane32_swap pack) ----
#pragma unroll
    for (int ks = 0; ks < 2; ++ks) {
      int rp = ks * 2;
      unsigned A0 = cvtpk(st[rp * 4 + 0], st[rp * 4 + 1]);
      unsigned A1 = cvtpk(st[rp * 4 + 2], st[rp * 4 + 3]);
      unsigned B0 = cvtpk(st[rp * 4 + 4], st[rp * 4 + 5]);
      unsigned B1 = cvtpk(st[rp * 4 + 6], st[rp * 4 + 7]);
      asm volatile("v_permlane32_swap_b32 %0, %1" : "+v"(A0), "+v"(B0));
      asm volatile("v_permlane32_swap_b32 %0, %1" : "+v"(A1), "+v"(B1));
      union { unsigned w[4]; bf16x8 v; } Bf;
      Bf.w[0] = A0; Bf.w[1] = A1; Bf.w[2] = B0; Bf.w[3] = B1;
      bf16x8 v0 = *(const bf16x8*)(sVc + l31 * 64 + (((ks * 2 + hi2) << 4) ^ rswz64));
      bf16x8 v1 = *(const bf16x8*)(sVc + (32 + l31) * 64 + (((ks * 2 + hi2) << 4) ^ rswz64));
      O = __builtin_amdgcn_mfma_f32_32x32x16_bf16(v0, Bf.v, O, 0, 0, 0);
      O2 = __builtin_amdgcn_mfma_f32_32x32x16_bf16(v1, Bf.v, O2, 0, 0, 0);
    }
    __syncthreads();  // readers done; drains next-tile stage
  }

  // ---- merge the two KV halves (group 1 -> LDS, group 0 combines + stores) ----
  float* mbuf = (float*)smem + w4 * (32 * 68);  // [q 32][d 68-padded] per wave-pair
  if (grp == 1) {
    if (hi2 == 0) { mlb[w4][0][l31] = m; mlb[w4][1][l31] = l; }
#pragma unroll
    for (int dt = 0; dt < 2; ++dt)
#pragma unroll
      for (int rq = 0; rq < 4; ++rq) {
        int d0 = dt * 32 + 8 * rq + 4 * hi2;
        const f32x16& Ox = dt ? O2 : O;
        f32x4 v = {Ox[rq * 4 + 0], Ox[rq * 4 + 1], Ox[rq * 4 + 2], Ox[rq * 4 + 3]};
        *(f32x4*)(mbuf + l31 * 68 + d0) = v;
      }
  }
  __syncthreads();
  if (grp == 0) {
    float m1 = mlb[w4][0][l31], l1 = mlb[w4][1][l31];
    float mx = fmaxf(m, m1);
    float a0 = exp2f(m - mx), a1 = exp2f(m1 - mx);
    float linv = 1.0f / (a0 * l + a1 * l1);
    a0 *= linv; a1 *= linv;
    float* orow = out + ((size_t)bi * S_LEN + qrow) * HIDN + h * HDIM;
#pragma unroll
    for (int dt = 0; dt < 2; ++dt)
#pragma unroll
      for (int rq = 0; rq < 4; ++rq) {
        int d0 = dt * 32 + 8 * rq + 4 * hi2;
        const f32x16& Ox = dt ? O2 : O;
        f32x4 v1 = *(const f32x4*)(mbuf + l31 * 68 + d0);
        float4 o;
        o.x = Ox[rq * 4 + 0] * a0 + v1[0] * a1;
        o.y = Ox[rq * 4 + 1] * a0 + v1[1] * a1;
        o.z = Ox[rq * 4 + 2] * a0 + v1[2] * a1;
        o.w = Ox[rq * 4 + 3] * a0 + v1[3] * a1;
        *(float4*)(orow + d0) = o;
      }
  }
}

extern "C" void kernel_launch(void* const* d_in, const int* in_sizes, int n_in,
                              void* d_out, int out_size, void* d_ws, size_t ws_size,
                              hipStream_t stream) {
  const float* hs    = (const float*)d_in[0];
  const float* amask = (const float*)d_in[1];
  const float* smask = (const float*)d_in[2];
  const float* Wq    = (const float*)d_in[3];
  const float* bq    = (const float*)d_in[4];
  const float* Wk    = (const float*)d_in[5];
  const float* bk    = (const float*)d_in[6];
  const float* Wv    = (const float*)d_in[7];
  const float* bv    = (const float*)d_in[8];
  const float* gate  = (const float*)d_in[9];

  char* ws = (char*)d_ws;
  __hip_bfloat16* Abf  = (__hip_bfloat16*)(ws);
  __hip_bfloat16* Wcat = (__hip_bfloat16*)(ws + 8388608);
  __hip_bfloat16* qb   = (__hip_bfloat16*)(ws + 8388608 + 6291456);
  __hip_bfloat16* kb   = qb + NA;
  __hip_bfloat16* vb   = kb + NA;
  __hip_bfloat16* Mbf  = vb + NA;
  float*          amg  = (float*)(Mbf + NM);
  __hip_bfloat16* vt   = Abf;  // alias: Abf dead after qkv_gemm

  convert_kernel<<<2048, 256, 0, stream>>>(hs, Wq, Wk, Wv, smask, amask, Abf, Wcat, Mbf, amg);
  qkv_gemm<<<768, 256, 0, stream>>>(Abf, Wcat, bq, bk, bv, qb, kb, vb);
  vtrans_kernel<<<1024, 256, 0, stream>>>(vb, vt);
  attn_kernel<<<512, 512, 0, stream>>>(qb, kb, vt, Mbf, amg, gate, (float*)d_out);
}

// Round 6
// 144.573 us; speedup vs baseline: 1.7035x; 1.0432x over previous
//
#include <hip/hip_runtime.h>
#include <hip/hip_bf16.h>
#include <cmath>

// Problem constants
#define S_LEN 2048
#define HIDN  1024
#define NHEAD 16
#define HDIM  64
#define NBAT  2

static constexpr long NA = (long)NBAT * S_LEN * HIDN;  // hidden elems
static constexpr long NW = (long)HIDN * HIDN;          // per weight
static constexpr long NM = (long)NBAT * S_LEN * S_LEN; // struct mask elems
static constexpr long NAM = (long)NBAT * S_LEN;        // amask elems

typedef __attribute__((ext_vector_type(8))) __bf16 bf16x8;
typedef __attribute__((ext_vector_type(4))) float f32x4;
typedef __attribute__((ext_vector_type(16))) float f32x16;
typedef __attribute__((ext_vector_type(4))) unsigned short u16x4;

#define LOG2E 1.44269504088896340736f

__device__ __forceinline__ unsigned short f2bf(float f) {
  __hip_bfloat16 h = __float2bfloat16(f);
  unsigned short u;
  __builtin_memcpy(&u, &h, 2);
  return u;
}

__device__ __forceinline__ float bfu2f(unsigned short u) {
  unsigned v = (unsigned)u << 16;
  float f;
  __builtin_memcpy(&f, &v, 4);
  return f;
}

// packed f32->bf16 RNE: low16 = bf16(a), high16 = bf16(b); 1 instr
__device__ __forceinline__ unsigned cvtpk(float a, float b) {
  unsigned r;
  asm volatile("v_cvt_pk_bf16_f32 %0, %1, %2" : "=v"(r) : "v"(a), "v"(b));
  return r;
}

__device__ __forceinline__ void gload_lds16(const void* g, void* l) {
  __builtin_amdgcn_global_load_lds(
      (const __attribute__((address_space(1))) void*)g,
      (__attribute__((address_space(3))) void*)l, 16, 0, 0);
}

// ---------------- kernel 1: fp32 -> bf16 conversions (+ amask prescale) ----------------
__global__ __launch_bounds__(256) void convert_kernel(
    const float* __restrict__ hs, const float* __restrict__ wq,
    const float* __restrict__ wk, const float* __restrict__ wv,
    const float* __restrict__ mask, const float* __restrict__ amask,
    __hip_bfloat16* __restrict__ Abf, __hip_bfloat16* __restrict__ Wcat,
    __hip_bfloat16* __restrict__ Mbf, float* __restrict__ amg) {
  const long tot4 = (NA + 3 * NW + NM + NAM) >> 2;
  for (long i4 = (long)blockIdx.x * blockDim.x + threadIdx.x; i4 < tot4;
       i4 += (long)gridDim.x * blockDim.x) {
    long i = i4 << 2;
    if (i < NA + 3 * NW + NM) {
      const float* s;
      __hip_bfloat16* dq;
      if (i < NA)               { s = hs + i;                   dq = Abf + i; }
      else if (i < NA + NW)     { s = wq + (i - NA);            dq = Wcat + (i - NA); }
      else if (i < NA + 2 * NW) { s = wk + (i - NA - NW);       dq = Wcat + (i - NA); }
      else if (i < NA + 3 * NW) { s = wv + (i - NA - 2 * NW);   dq = Wcat + (i - NA); }
      else                      { s = mask + (i - NA - 3 * NW); dq = Mbf + (i - NA - 3 * NW); }
      float4 v = *(const float4*)s;
      union { unsigned short u[4]; uint2 p; } o;
      o.u[0] = f2bf(v.x); o.u[1] = f2bf(v.y); o.u[2] = f2bf(v.z); o.u[3] = f2bf(v.w);
      *(uint2*)dq = o.p;
    } else {
      long j = i - (NA + 3 * NW + NM);
      float4 v = *(const float4*)(amask + j);
      v.x *= LOG2E; v.y *= LOG2E; v.z *= LOG2E; v.w *= LOG2E;
      *(float4*)(amg + j) = v;
    }
  }
}

// ---------------- kernel 2: QKV GEMM (m97 structure) ----------------
// q output pre-scaled by c2 = log2(e)/sqrt(HD) so attn scores are log2-domain
__global__ __launch_bounds__(256) void qkv_gemm(
    const __hip_bfloat16* __restrict__ A, const __hip_bfloat16* __restrict__ Bw,
    const float* __restrict__ bq, const float* __restrict__ bk,
    const float* __restrict__ bv, __hip_bfloat16* __restrict__ qb,
    __hip_bfloat16* __restrict__ kb, __hip_bfloat16* __restrict__ vb) {
  __shared__ __hip_bfloat16 sA[128 * 32];
  __shared__ __hip_bfloat16 sB[128 * 32];

  int bid = blockIdx.x;
  int cpx = gridDim.x >> 3;
  int wg = (bid & 7) * cpx + (bid >> 3);
  int bm = wg / 24, bn = wg % 24;
  int tid = threadIdx.x, lane = tid & 63, wid = tid >> 6;
  int wr = wid >> 1, wc = wid & 1;
  int lr = lane & 15, hi = lane >> 4;
  int srow = lane >> 2, scol = (lane & 3) * 8;

  f32x4 acc[4][4] = {};

  for (int kt = 0; kt < 32; ++kt) {
    int k0 = kt * 32;
#pragma unroll
    for (int cc = 0; cc < 2; ++cc) {
      int c = wid * 2 + cc;
      const __hip_bfloat16* ga =
          A + ((size_t)(bm * 128 + c * 16 + srow) * 1024 + k0 + scol);
      gload_lds16(ga, (char*)sA + c * 1024);
      const __hip_bfloat16* gb =
          Bw + ((size_t)(bn * 128 + c * 16 + srow) * 1024 + k0 + scol);
      gload_lds16(gb, (char*)sB + c * 1024);
    }
    __syncthreads();
    bf16x8 af[4], bf[4];
#pragma unroll
    for (int mt = 0; mt < 4; ++mt)
      af[mt] = *(const bf16x8*)((const char*)sA +
                                ((wr * 64 + mt * 16 + lr) * 32 + hi * 8) * 2);
#pragma unroll
    for (int nt = 0; nt < 4; ++nt)
      bf[nt] = *(const bf16x8*)((const char*)sB +
                                ((wc * 64 + nt * 16 + lr) * 32 + hi * 8) * 2);
#pragma unroll
    for (int mt = 0; mt < 4; ++mt)
#pragma unroll
      for (int nt = 0; nt < 4; ++nt)
        acc[mt][nt] =
            __builtin_amdgcn_mfma_f32_16x16x32_bf16(af[mt], bf[nt], acc[mt][nt], 0, 0, 0);
    __syncthreads();
  }

  const float c2 = LOG2E / 8.0f;
#pragma unroll
  for (int nt = 0; nt < 4; ++nt) {
    int nb = bn * 128 + wc * 64 + nt * 16;
    int t = nb >> 10;
    int rem = nb & 1023;
    const float* bp = (t == 0) ? bq : (t == 1) ? bk : bv;
    __hip_bfloat16* ob = (t == 0) ? qb : (t == 1) ? kb : vb;
    float scl = (t == 0) ? c2 : 1.0f;
    int h = rem >> 6, d0 = rem & 63;
    float bias = bp[rem + lr];
    int d = d0 + lr;
#pragma unroll
    for (int mt = 0; mt < 4; ++mt) {
#pragma unroll
      for (int r = 0; r < 4; ++r) {
        int m = bm * 128 + wr * 64 + mt * 16 + hi * 4 + r;
        int b = m >> 11, s = m & 2047;
        size_t off = (((size_t)(b * NHEAD + h)) * S_LEN + s) * HDIM + d;
        ob[off] = __float2bfloat16((acc[mt][nt][r] + bias) * scl);
      }
    }
  }
}

// ---------------- kernel 3: V -> V^T  ([bh][s][d] -> [bh][d][s]) ----------------
__global__ __launch_bounds__(256) void vtrans_kernel(
    const __hip_bfloat16* __restrict__ vb, __hip_bfloat16* __restrict__ vt) {
  __shared__ __hip_bfloat16 tile[64][72];
  int bh = blockIdx.x >> 5;
  int st = blockIdx.x & 31;
  int t = threadIdx.x;
  int r8 = t >> 3, c8 = (t & 7) * 8;
#pragma unroll
  for (int p = 0; p < 2; ++p) {
    int row = p * 32 + r8;
    bf16x8 v = *(const bf16x8*)(vb + ((size_t)bh * S_LEN + st * 64 + row) * HDIM + c8);
    *(bf16x8*)&tile[row][c8] = v;
  }
  __syncthreads();
#pragma unroll
  for (int p = 0; p < 2; ++p) {
    int d = p * 32 + r8;
    union { unsigned short u[8]; bf16x8 v; } o;
#pragma unroll
    for (int j = 0; j < 8; ++j) {
      __hip_bfloat16 e = tile[c8 + j][d];
      __builtin_memcpy(&o.u[j], &e, 2);
    }
    *(bf16x8*)(vt + ((size_t)bh * HDIM + d) * S_LEN + st * 64 + c8) = o.v;
  }
}

// ---------------- kernel 4: KV-split flash attention, swapped-QK^T ----------------
// 512 blocks x 512 threads (8 waves). Group 0: KV rows 0-1023; group 1: 1024-2047.
// KVBLK=64 staging (2x32-key compute sub-steps). K and V^T in LDS with 128B rows +
// 8-position XOR swizzle (conflict-free ds_read_b128). Struct mask: per-lane register
// prefetch from global, 1.5 tiles ahead. amask: staged once to LDS. Merge via LDS.
__global__ __launch_bounds__(512, 4) void attn_kernel(
    const __hip_bfloat16* __restrict__ qb, const __hip_bfloat16* __restrict__ kbuf,
    const __hip_bfloat16* __restrict__ vt, const __hip_bfloat16* __restrict__ Mbf,
    const float* __restrict__ amg, const float* __restrict__ gate,
    float* __restrict__ out) {
  // [0,65536): KV [buf2][grp2][K 8KB | V 8KB]; [65536,73728): am [grp2][1024 f32]
  __shared__ alignas(16) char smem[73728];
  __shared__ float mlb[4][2][32];

  int bid = blockIdx.x;
  int wg = (bid & 7) * 64 + (bid >> 3);  // XCD swizzle (bijective, 512 = 8*64)
  int bi = wg >> 8;
  int h = (wg >> 4) & 15;
  int qt = wg & 15;
  int bh = bi * NHEAD + h;

  int tid = threadIdx.x;
  int lane = tid & 63, wid = tid >> 6;
  int grp = wid >> 2, w4 = wid & 3;
  int l31 = lane & 31, hi2 = lane >> 5;
  int qbase = qt * 128 + w4 * 32;
  int qrow = qbase + l31;
  int kbase = grp << 10;
  float g2 = gate[h] * LOG2E;

  const char* Kb = (const char*)kbuf + (size_t)bh * S_LEN * 128;
  const char* Vb = (const char*)vt + (size_t)bh * HDIM * S_LEN * 2;
  // per-lane struct-mask row pointer (lane owns q-row l31; hi2 half-offset folded in)
  const char* Mrow = (const char*)Mbf + ((size_t)bi * S_LEN + qrow) * S_LEN * 2 + hi2 * 8;

  // Q fragments (pre-scaled by log2e/8 in GEMM epilogue)
  bf16x8 qf[4];
  {
    const __hip_bfloat16* qp = qb + ((size_t)bh * S_LEN + qrow) * HDIM + hi2 * 8;
#pragma unroll
    for (int dc = 0; dc < 4; ++dc) qf[dc] = *(const bf16x8*)(qp + dc * 16);
  }

  int r8 = lane >> 3, ch = lane & 7;
  float* amL = (float*)(smem + 65536 + grp * 4096);

  auto stage = [&](int buf, int t) {
    int k0 = kbase + t * 64;
    char* kdst = smem + buf * 32768 + grp * 16384 + w4 * 2048;
    char* vdst = kdst + 8192;
#pragma unroll
    for (int c = 0; c < 2; ++c) {
      int row = w4 * 16 + c * 8 + r8;  // row&7 == r8; swizzle involution chunk^=r8
      gload_lds16(Kb + (size_t)(k0 + row) * 128 + ((ch ^ r8) << 4), kdst + c * 1024);
      gload_lds16(Vb + (size_t)row * 4096 + (size_t)k0 * 2 + ((ch ^ r8) << 4),
                  vdst + c * 1024);
    }
  };

  // mask register prefetch: mn0 holds sub-tile ss=0 of next tile, mn1 ss=1
  u16x4 mn0[4], mn1[4];
#pragma unroll
  for (int rp = 0; rp < 4; ++rp) {
    mn0[rp] = *(const u16x4*)(Mrow + (size_t)(kbase + rp * 8) * 2);
    mn1[rp] = *(const u16x4*)(Mrow + (size_t)(kbase + 32 + rp * 8) * 2);
  }

  // prologue staging: KV tile 0 + amask (1KB per wave, once)
  stage(0, 0);
  gload_lds16((const char*)amg + ((size_t)bi * S_LEN + kbase + w4 * 256) * 4,
              (char*)amL + w4 * 1024);
  __syncthreads();

  f32x16 O = {}, O2 = {};
  float m = -INFINITY, l = 0.f;

  for (int t = 0; t < 16; ++t) {
    int cur = t & 1;
    if (t < 15) stage(cur ^ 1, t + 1);
    const char* sK = smem + cur * 32768 + grp * 16384;
    const char* sV = sK + 8192;

#pragma unroll
    for (int ss = 0; ss < 2; ++ss) {
      int klocal = t * 64 + ss * 32;

      // ---- S^T = K * Q^T (32-key sub-tile) ----
      f32x16 st = {};
#pragma unroll
      for (int dc = 0; dc < 4; ++dc) {
        int row = ss * 32 + l31;
        bf16x8 kf = *(const bf16x8*)(sK + row * 128 +
                                     (((dc * 2 + hi2) ^ (l31 & 7)) << 4));
        st = __builtin_amdgcn_mfma_f32_32x32x16_bf16(kf, qf[dc], st, 0, 0, 0);
      }

      // ---- masks + row max (lane-local, q = l31) ----
      float pmax = -3.4e38f;
#pragma unroll
      for (int rp = 0; rp < 4; ++rp) {
        float4 am = *(const float4*)(amL + klocal + rp * 8 + hi2 * 4);
        union { u16x4 v; unsigned short e[4]; } mv;
        mv.v = ss ? mn1[rp] : mn0[rp];
        float s0 = fmaf(bfu2f(mv.e[0]), g2, st[rp * 4 + 0] + am.x);
        float s1 = fmaf(bfu2f(mv.e[1]), g2, st[rp * 4 + 1] + am.y);
        float s2 = fmaf(bfu2f(mv.e[2]), g2, st[rp * 4 + 2] + am.z);
        float s3 = fmaf(bfu2f(mv.e[3]), g2, st[rp * 4 + 3] + am.w);
        st[rp * 4 + 0] = s0; st[rp * 4 + 1] = s1;
        st[rp * 4 + 2] = s2; st[rp * 4 + 3] = s3;
        pmax = fmaxf(pmax, fmaxf(fmaxf(s0, s1), fmaxf(s2, s3)));
      }

      // refill mask regs for tile t+1 (issued ~1.5 tiles ahead of consumption)
      if (t < 15) {
        int kn = kbase + (t + 1) * 64 + ss * 32;
#pragma unroll
        for (int rp = 0; rp < 4; ++rp) {
          u16x4 nv = *(const u16x4*)(Mrow + (size_t)(kn + rp * 8) * 2);
          if (ss) mn1[rp] = nv; else mn0[rp] = nv;
        }
      }

      pmax = fmaxf(pmax, __shfl_xor(pmax, 32));
      if (__any(pmax > m + 8.f)) {  // defer-max (T13)
        float mnew = fmaxf(m, pmax);
        float alpha = exp2f(m - mnew);
        m = mnew;
        l *= alpha;
        O *= alpha;
        O2 *= alpha;
      }

      // ---- exp2 + sum ----
      float rs0 = 0.f, rs1 = 0.f, rs2 = 0.f, rs3 = 0.f;
#pragma unroll
      for (int rp = 0; rp < 4; ++rp) {
        float p0 = exp2f(st[rp * 4 + 0] - m);
        float p1 = exp2f(st[rp * 4 + 1] - m);
        float p2 = exp2f(st[rp * 4 + 2] - m);
        float p3 = exp2f(st[rp * 4 + 3] - m);
        st[rp * 4 + 0] = p0; st[rp * 4 + 1] = p1;
        st[rp * 4 + 2] = p2; st[rp * 4 + 3] = p3;
        rs0 += p0; rs1 += p1; rs2 += p2; rs3 += p3;
      }
      float rs = (rs0 + rs1) + (rs2 + rs3);
      rs += __shfl_xor(rs, 32);
      l += rs;

      // ---- PV: O^T += V^T * P^T (cvt_pk + permlane32_swap pack) ----
#pragma unroll
      for (int ks = 0; ks < 2; ++ks) {
        int rp = ks * 2;
        unsigned A0 = cvtpk(st[rp * 4 + 0], st[rp * 4 + 1]);
        unsigned A1 = cvtpk(st[rp * 4 + 2], st[rp * 4 + 3]);
        unsigned B0 = cvtpk(st[rp * 4 + 4], st[rp * 4 + 5]);
        unsigned B1 = cvtpk(st[rp * 4 + 6], st[rp * 4 + 7]);
        asm volatile("v_permlane32_swap_b32 %0, %1" : "+v"(A0), "+v"(B0));
        asm volatile("v_permlane32_swap_b32 %0, %1" : "+v"(A1), "+v"(B1));
        union { unsigned w[4]; bf16x8 v; } Bf;
        Bf.w[0] = A0; Bf.w[1] = A1; Bf.w[2] = B0; Bf.w[3] = B1;
        int vc = ss * 4 + ks * 2 + hi2;
        bf16x8 v0 = *(const bf16x8*)(sV + l31 * 128 + ((vc ^ (l31 & 7)) << 4));
        bf16x8 v1 = *(const bf16x8*)(sV + (32 + l31) * 128 + ((vc ^ (l31 & 7)) << 4));
        O = __builtin_amdgcn_mfma_f32_32x32x16_bf16(v0, Bf.v, O, 0, 0, 0);
        O2 = __builtin_amdgcn_mfma_f32_32x32x16_bf16(v1, Bf.v, O2, 0, 0, 0);
      }
    }
    __syncthreads();  // readers done; drains next-tile stage
  }

  // ---- merge the two KV halves (group 1 -> LDS, group 0 combines + stores) ----
  float* mbuf = (float*)smem + w4 * (32 * 68);  // [q 32][d 68-padded] per wave-pair
  if (grp == 1) {
    if (hi2 == 0) { mlb[w4][0][l31] = m; mlb[w4][1][l31] = l; }
#pragma unroll
    for (int dt = 0; dt < 2; ++dt)
#pragma unroll
      for (int rq = 0; rq < 4; ++rq) {
        int d0 = dt * 32 + 8 * rq + 4 * hi2;
        const f32x16& Ox = dt ? O2 : O;
        f32x4 v = {Ox[rq * 4 + 0], Ox[rq * 4 + 1], Ox[rq * 4 + 2], Ox[rq * 4 + 3]};
        *(f32x4*)(mbuf + l31 * 68 + d0) = v;
      }
  }
  __syncthreads();
  if (grp == 0) {
    float m1 = mlb[w4][0][l31], l1 = mlb[w4][1][l31];
    float mx = fmaxf(m, m1);
    float a0 = exp2f(m - mx), a1 = exp2f(m1 - mx);
    float linv = 1.0f / (a0 * l + a1 * l1);
    a0 *= linv; a1 *= linv;
    float* orow = out + ((size_t)bi * S_LEN + qrow) * HIDN + h * HDIM;
#pragma unroll
    for (int dt = 0; dt < 2; ++dt)
#pragma unroll
      for (int rq = 0; rq < 4; ++rq) {
        int d0 = dt * 32 + 8 * rq + 4 * hi2;
        const f32x16& Ox = dt ? O2 : O;
        f32x4 v1 = *(const f32x4*)(mbuf + l31 * 68 + d0);
        float4 o;
        o.x = Ox[rq * 4 + 0] * a0 + v1[0] * a1;
        o.y = Ox[rq * 4 + 1] * a0 + v1[1] * a1;
        o.z = Ox[rq * 4 + 2] * a0 + v1[2] * a1;
        o.w = Ox[rq * 4 + 3] * a0 + v1[3] * a1;
        *(float4*)(orow + d0) = o;
      }
  }
}

extern "C" void kernel_launch(void* const* d_in, const int* in_sizes, int n_in,
                              void* d_out, int out_size, void* d_ws, size_t ws_size,
                              hipStream_t stream) {
  const float* hs    = (const float*)d_in[0];
  const float* amask = (const float*)d_in[1];
  const float* smask = (const float*)d_in[2];
  const float* Wq    = (const float*)d_in[3];
  const float* bq    = (const float*)d_in[4];
  const float* Wk    = (const float*)d_in[5];
  const float* bk    = (const float*)d_in[6];
  const float* Wv    = (const float*)d_in[7];
  const float* bv    = (const float*)d_in[8];
  const float* gate  = (const float*)d_in[9];

  char* ws = (char*)d_ws;
  __hip_bfloat16* Abf  = (__hip_bfloat16*)(ws);
  __hip_bfloat16* Wcat = (__hip_bfloat16*)(ws + 8388608);
  __hip_bfloat16* qb   = (__hip_bfloat16*)(ws + 8388608 + 6291456);
  __hip_bfloat16* kb   = qb + NA;
  __hip_bfloat16* vb   = kb + NA;
  __hip_bfloat16* Mbf  = vb + NA;
  float*          amg  = (float*)(Mbf + NM);
  __hip_bfloat16* vt   = Abf;  // alias: Abf dead after qkv_gemm

  convert_kernel<<<2048, 256, 0, stream>>>(hs, Wq, Wk, Wv, smask, amask, Abf, Wcat, Mbf, amg);
  qkv_gemm<<<768, 256, 0, stream>>>(Abf, Wcat, bq, bk, bv, qb, kb, vb);
  vtrans_kernel<<<1024, 256, 0, stream>>>(vb, vt);
  attn_kernel<<<512, 512, 0, stream>>>(qb, kb, vt, Mbf, amg, gate, (float*)d_out);
}